// Round 2
// baseline (136.126 us; speedup 1.0000x reference)
//
#include <hip/hip_runtime.h>
#include <hip/hip_bf16.h>
#include <cmath>

#define T_STEPS 128
#define BATCH   64
#define NI      784
#define NIP     800      // padded K (25 * 32)
#define NH      512
#define NO      10
#define M1      (T_STEPS*BATCH)       // 8192
#define NT_H    (BATCH*NH)            // 32768
#define NT_O    (BATCH*NO)            // 640
#define OUT_HALF (T_STEPS*BATCH*NO)   // 81920

typedef __attribute__((ext_vector_type(8))) short short8;
typedef __attribute__((ext_vector_type(4))) float f32x4;
typedef __attribute__((ext_vector_type(8))) unsigned short u16x8;

static __device__ __forceinline__ unsigned short f2b_bits(float x) {
    __hip_bfloat16 h = __float2bfloat16(x);
    return *reinterpret_cast<unsigned short*>(&h);
}
static __device__ __forceinline__ float b2f_bits(unsigned short u) {
    union { unsigned int i; float f; } v; v.i = ((unsigned int)u) << 16; return v.f;
}

// --- c table: c[j] = (j+1)^0.8 - j^0.8 --------------------------------------
__global__ void init_c_kernel(float* __restrict__ c) {
    int j = threadIdx.x;
    if (j <= T_STEPS + 2) {
        double a = pow((double)(j + 1), 0.8);
        double b = pow((double)j, 0.8);
        c[j] = (float)(a - b);
    }
}

// --- cast + pad f32 -> bf16, optional (b,t)->(t,b) row permute --------------
// dst [rows][800]; mode0: src [rows][784]; mode1: src data[b][t][784], dst row r=t*64+b
__global__ __launch_bounds__(256) void cast_pad_kernel(const float* __restrict__ src,
                                                       __hip_bfloat16* __restrict__ dst,
                                                       int rows, int mode) {
    int idx = blockIdx.x * 256 + threadIdx.x;
    if (idx >= rows * 200) return;
    int r  = idx / 200;
    int n4 = (idx - r * 200) * 4;
    int srow = r;
    if (mode == 1) { int t = r >> 6, b = r & 63; srow = b * T_STEPS + t; }
    ushort4 o;
    if (n4 < NI) {
        const float4 f = *reinterpret_cast<const float4*>(src + (size_t)srow * NI + n4);
        o.x = f2b_bits(f.x); o.y = f2b_bits(f.y); o.z = f2b_bits(f.z); o.w = f2b_bits(f.w);
    } else {
        o.x = o.y = o.z = o.w = 0;
    }
    *reinterpret_cast<ushort4*>(dst + (size_t)r * NIP + n4) = o;
}

// --- bf16 MFMA GEMM: C[M][N] = A[M][Kp] * B[N][Kp]^T  (both row-major) ------
// tile 128x128, 4 waves (2x2), each wave 64x64 = 4x4 frags of 16x16x32
__global__ __launch_bounds__(256) void gemm_bf16_kernel(const __hip_bfloat16* __restrict__ A,
                                                        const __hip_bfloat16* __restrict__ B,
                                                        __hip_bfloat16* __restrict__ C,
                                                        int N, int Kp) {
    __shared__ __hip_bfloat16 As[128 * 32];
    __shared__ __hip_bfloat16 Bs[128 * 32];
    const int tid  = threadIdx.x;
    const int wave = tid >> 6, lane = tid & 63;
    const int wm = wave >> 1, wn = wave & 1;
    const int bm = blockIdx.x, bn = blockIdx.y;
    const int lrow = lane >> 2;      // 0..15
    const int lchk = lane & 3;       // 0..3

    f32x4 acc[4][4] = {};

    for (int k0 = 0; k0 < Kp; k0 += 32) {
#pragma unroll
        for (int p = 0; p < 2; ++p) {
            const int rbase = p * 64 + wave * 16;
            {
                const __hip_bfloat16* g = A + (size_t)(bm * 128 + rbase + lrow) * Kp + k0 + lchk * 8;
                __builtin_amdgcn_global_load_lds((const __attribute__((address_space(1))) void*)g,
                                                 (__attribute__((address_space(3))) void*)(As + rbase * 32),
                                                 16, 0, 0);
            }
            {
                const __hip_bfloat16* g = B + (size_t)(bn * 128 + rbase + lrow) * Kp + k0 + lchk * 8;
                __builtin_amdgcn_global_load_lds((const __attribute__((address_space(1))) void*)g,
                                                 (__attribute__((address_space(3))) void*)(Bs + rbase * 32),
                                                 16, 0, 0);
            }
        }
        __syncthreads();

        short8 a[4], b[4];
#pragma unroll
        for (int i = 0; i < 4; ++i)
            a[i] = *reinterpret_cast<const short8*>(As + (wm * 64 + i * 16 + (lane & 15)) * 32 + (lane >> 4) * 8);
#pragma unroll
        for (int j = 0; j < 4; ++j)
            b[j] = *reinterpret_cast<const short8*>(Bs + (wn * 64 + j * 16 + (lane & 15)) * 32 + (lane >> 4) * 8);
#pragma unroll
        for (int i = 0; i < 4; ++i)
#pragma unroll
            for (int j = 0; j < 4; ++j)
                acc[i][j] = __builtin_amdgcn_mfma_f32_16x16x32_bf16(a[i], b[j], acc[i][j], 0, 0, 0);
        __syncthreads();
    }

    // C/D layout: col = lane&15, row = (lane>>4)*4 + reg
#pragma unroll
    for (int i = 0; i < 4; ++i) {
#pragma unroll
        for (int j = 0; j < 4; ++j) {
            const int col = bn * 128 + wn * 64 + j * 16 + (lane & 15);
#pragma unroll
            for (int r2 = 0; r2 < 4; ++r2) {
                const int row = bm * 128 + wm * 64 + i * 16 + (lane >> 4) * 4 + r2;
                C[(size_t)row * N + col] = __float2bfloat16(acc[i][j][r2]);
            }
        }
    }
}

// --- fractional LIF scan: one thread per neuron, template-recursion unroll --
// Every history/c-table index is a compile-time constant (constexpr cnt), so
// SROA must promote h[] and c[] to VGPRs (gfx950 unified 512-reg file; ~290
// live regs, no spill expected). Arithmetic expression is token-identical to
// the previous passing kernel (chunk-of-4, single accumulator, scalar tail).
#define PF_DEPTH 8

template <bool FINAL, int N>
__device__ __forceinline__ void flif_steps(const void* __restrict__ Iin,
                                           void* __restrict__ spikes,
                                           float* __restrict__ mems,
                                           const float* __restrict__ c,
                                           float* __restrict__ h,
                                           float* __restrict__ pf,
                                           float& V, int NT, int nid, float kappa) {
    constexpr int n   = N;
    constexpr int cnt = n - 1;        // history slots 0..cnt-1, weight c[cnt-k]

    const float Iv = pf[(n - 1) & (PF_DEPTH - 1)];
    if constexpr (n + PF_DEPTH <= T_STEPS) {
        constexpr int s = n - 1 + PF_DEPTH;   // 0-based step index to prefetch
        if (FINAL) pf[(n - 1) & (PF_DEPTH - 1)] = ((const float*)Iin)[(size_t)s * NT + nid];
        else       pf[(n - 1) & (PF_DEPTH - 1)] = __bfloat162float(((const __hip_bfloat16*)Iin)[(size_t)s * NT + nid]);
    }

    float mem = 0.f;
    constexpr int c4 = cnt & ~3;
#pragma unroll
    for (int k = 0; k < c4; k += 4) {
        mem += h[k]     * c[cnt - k]     + h[k + 1] * c[cnt - k - 1]
             + h[k + 2] * c[cnt - k - 2] + h[k + 3] * c[cnt - k - 3];
    }
#pragma unroll
    for (int k = c4; k < cnt; ++k) mem += h[k] * c[cnt - k];

    const float f  = (-0.025f * (V + 70.f) + Iv) * 2.0f;   // /CM, CM=0.5
    const float Vn = kappa * f + V - mem;
    const bool  sp = (Vn >= -50.f);
    const float Vr = sp ? -70.f : Vn;
    h[n - 1] = Vr - V;
    if (FINAL) {
        ((float*)spikes)[(size_t)(n - 1) * NT + nid] = sp ? 1.f : 0.f;
        mems[(size_t)(n - 1) * NT + nid] = Vr;
    } else {
        ((__hip_bfloat16*)spikes)[(size_t)(n - 1) * NT + nid] = __float2bfloat16(sp ? 1.f : 0.f);
    }
    V = Vr;

    if constexpr (N < T_STEPS)
        flif_steps<FINAL, N + 1>(Iin, spikes, mems, c, h, pf, V, NT, nid, kappa);
}

// FINAL=false: Iin bf16, write spikes bf16 (for GEMM2)
// FINAL=true : Iin f32,  write spikes f32 + mems f32 (d_out)
template <bool FINAL>
__global__ __launch_bounds__(64, 1) void flif_scan_kernel(const void* __restrict__ Iin,
                                                          void* __restrict__ spikes,
                                                          float* __restrict__ mems,
                                                          const float* __restrict__ ctab,
                                                          int NT, float kappa) {
    const int nid = blockIdx.x * 64 + threadIdx.x;

    // c-table into registers (static indices; values identical to before)
    float c[T_STEPS + 1];
#pragma unroll
    for (int j = 0; j <= T_STEPS; ++j) c[j] = ctab[j];

    float h[T_STEPS];   // history dV, register-resident (static indexing only)

    // rolling prefetch of the per-step input current (coalesced loads)
    float pf[PF_DEPTH];
#pragma unroll
    for (int d = 0; d < PF_DEPTH; ++d) {
        if (FINAL) pf[d] = ((const float*)Iin)[(size_t)d * NT + nid];
        else       pf[d] = __bfloat162float(((const __hip_bfloat16*)Iin)[(size_t)d * NT + nid]);
    }

    float V = -70.f;
    flif_steps<FINAL, 1>(Iin, spikes, mems, c, h, pf, V, NT, nid, kappa);
}

// --- GEMM2: Io[r][o] = sum_h S[r][h]*Wo[o][h], one wave per row (f32 out) ---
__global__ __launch_bounds__(256) void gemm2_kernel(const __hip_bfloat16* __restrict__ S,
                                                    const float* __restrict__ Wo,
                                                    float* __restrict__ Io) {
    const int wave = threadIdx.x >> 6, lane = threadIdx.x & 63;
    const int r = blockIdx.x * 4 + wave;
    u16x8 raw = *reinterpret_cast<const u16x8*>(S + (size_t)r * NH + lane * 8);
    float s[8];
#pragma unroll
    for (int j = 0; j < 8; ++j) s[j] = b2f_bits(raw[j]);
#pragma unroll
    for (int o = 0; o < NO; ++o) {
        const float* w = Wo + (size_t)o * NH + lane * 8;
        float a = 0.f;
#pragma unroll
        for (int j = 0; j < 8; ++j) a += s[j] * w[j];
#pragma unroll
        for (int off = 32; off; off >>= 1) a += __shfl_xor(a, off);
        if (lane == o) Io[(size_t)r * NO + o] = a;
    }
}

extern "C" void kernel_launch(void* const* d_in, const int* in_sizes, int n_in,
                              void* d_out, int out_size, void* d_ws, size_t ws_size,
                              hipStream_t stream) {
    const float* data = (const float*)d_in[0];   // [64][128][784]
    const float* Wh   = (const float*)d_in[1];   // [512][784]
    const float* Wo   = (const float*)d_in[2];   // [10][512]
    float* out = (float*)d_out;                  // f32! spikes then mems

    char* ws = (char*)d_ws;
    size_t off = 0;
    auto alloc = [&](size_t bytes) { void* p = ws + off; off += (bytes + 255) & ~255ull; return p; };
    __hip_bfloat16* Ab   = (__hip_bfloat16*)alloc((size_t)M1 * NIP * 2);  // 13.1 MB
    __hip_bfloat16* Whb  = (__hip_bfloat16*)alloc((size_t)NH * NIP * 2);  // 0.8 MB
    __hip_bfloat16* Ih   = (__hip_bfloat16*)alloc((size_t)M1 * NH * 2);   // 8.4 MB
    __hip_bfloat16* Sh   = (__hip_bfloat16*)alloc((size_t)M1 * NH * 2);   // 8.4 MB
    float*          Io   = (float*)alloc((size_t)M1 * NO * 4);            // 0.33 MB
    float*          ctab = (float*)alloc(192 * 4);

    const float kappa = (float)(std::pow(0.1, 0.2) * std::tgamma(1.8));

    init_c_kernel<<<1, 256, 0, stream>>>(ctab);
    cast_pad_kernel<<<(M1 * 200 + 255) / 256, 256, 0, stream>>>(data, Ab, M1, 1);
    cast_pad_kernel<<<(NH * 200 + 255) / 256, 256, 0, stream>>>(Wh, Whb, NH, 0);

    dim3 g1(64, 4, 1);   // M/128 x N/128
    gemm_bf16_kernel<<<g1, 256, 0, stream>>>(Ab, Whb, Ih, NH, NIP);

    flif_scan_kernel<false><<<NT_H / 64, 64, 0, stream>>>(Ih, Sh, nullptr, ctab, NT_H, kappa);

    gemm2_kernel<<<M1 / 4, 256, 0, stream>>>(Sh, Wo, Io);

    flif_scan_kernel<true><<<NT_O / 64, 64, 0, stream>>>(Io, out, out + OUT_HALF, ctab, NT_O, kappa);
}

// Round 3
// 105.464 us; speedup vs baseline: 1.2907x; 1.2907x over previous
//
#include <hip/hip_runtime.h>
#include <hip/hip_bf16.h>
#include <cmath>

#define T_STEPS 128
#define BATCH   64
#define NI      784
#define NIP     800      // padded K (25 * 32)
#define NH      512
#define NO      10
#define M1      (T_STEPS*BATCH)       // 8192
#define NT_H    (BATCH*NH)            // 32768
#define NT_O    (BATCH*NO)            // 640
#define OUT_HALF (T_STEPS*BATCH*NO)   // 81920
#define TB      16                    // time-tile for the scan

typedef __attribute__((ext_vector_type(8))) short short8;
typedef __attribute__((ext_vector_type(4))) float f32x4;
typedef __attribute__((ext_vector_type(8))) unsigned short u16x8;

static __device__ __forceinline__ unsigned short f2b_bits(float x) {
    __hip_bfloat16 h = __float2bfloat16(x);
    return *reinterpret_cast<unsigned short*>(&h);
}
static __device__ __forceinline__ float b2f_bits(unsigned short u) {
    union { unsigned int i; float f; } v; v.i = ((unsigned int)u) << 16; return v.f;
}

// --- c table: c[j] = (j+1)^0.8 - j^0.8 --------------------------------------
__global__ void init_c_kernel(float* __restrict__ c) {
    int j = threadIdx.x;
    if (j < 192) {
        double a = pow((double)(j + 1), 0.8);
        double b = pow((double)j, 0.8);
        c[j] = (float)(a - b);
    }
}

// --- cast + pad f32 -> bf16, optional (b,t)->(t,b) row permute --------------
// dst [rows][800]; mode0: src [rows][784]; mode1: src data[b][t][784], dst row r=t*64+b
__global__ __launch_bounds__(256) void cast_pad_kernel(const float* __restrict__ src,
                                                       __hip_bfloat16* __restrict__ dst,
                                                       int rows, int mode) {
    int idx = blockIdx.x * 256 + threadIdx.x;
    if (idx >= rows * 200) return;
    int r  = idx / 200;
    int n4 = (idx - r * 200) * 4;
    int srow = r;
    if (mode == 1) { int t = r >> 6, b = r & 63; srow = b * T_STEPS + t; }
    ushort4 o;
    if (n4 < NI) {
        const float4 f = *reinterpret_cast<const float4*>(src + (size_t)srow * NI + n4);
        o.x = f2b_bits(f.x); o.y = f2b_bits(f.y); o.z = f2b_bits(f.z); o.w = f2b_bits(f.w);
    } else {
        o.x = o.y = o.z = o.w = 0;
    }
    *reinterpret_cast<ushort4*>(dst + (size_t)r * NIP + n4) = o;
}

// --- bf16 MFMA GEMM: C[M][N] = A[M][Kp] * B[N][Kp]^T  (both row-major) ------
// tile 128x128, 4 waves (2x2), each wave 64x64 = 4x4 frags of 16x16x32
__global__ __launch_bounds__(256) void gemm_bf16_kernel(const __hip_bfloat16* __restrict__ A,
                                                        const __hip_bfloat16* __restrict__ B,
                                                        __hip_bfloat16* __restrict__ C,
                                                        int N, int Kp) {
    __shared__ __hip_bfloat16 As[128 * 32];
    __shared__ __hip_bfloat16 Bs[128 * 32];
    const int tid  = threadIdx.x;
    const int wave = tid >> 6, lane = tid & 63;
    const int wm = wave >> 1, wn = wave & 1;
    const int bm = blockIdx.x, bn = blockIdx.y;
    const int lrow = lane >> 2;      // 0..15
    const int lchk = lane & 3;       // 0..3

    f32x4 acc[4][4] = {};

    for (int k0 = 0; k0 < Kp; k0 += 32) {
#pragma unroll
        for (int p = 0; p < 2; ++p) {
            const int rbase = p * 64 + wave * 16;
            {
                const __hip_bfloat16* g = A + (size_t)(bm * 128 + rbase + lrow) * Kp + k0 + lchk * 8;
                __builtin_amdgcn_global_load_lds((const __attribute__((address_space(1))) void*)g,
                                                 (__attribute__((address_space(3))) void*)(As + rbase * 32),
                                                 16, 0, 0);
            }
            {
                const __hip_bfloat16* g = B + (size_t)(bn * 128 + rbase + lrow) * Kp + k0 + lchk * 8;
                __builtin_amdgcn_global_load_lds((const __attribute__((address_space(1))) void*)g,
                                                 (__attribute__((address_space(3))) void*)(Bs + rbase * 32),
                                                 16, 0, 0);
            }
        }
        __syncthreads();

        short8 a[4], b[4];
#pragma unroll
        for (int i = 0; i < 4; ++i)
            a[i] = *reinterpret_cast<const short8*>(As + (wm * 64 + i * 16 + (lane & 15)) * 32 + (lane >> 4) * 8);
#pragma unroll
        for (int j = 0; j < 4; ++j)
            b[j] = *reinterpret_cast<const short8*>(Bs + (wn * 64 + j * 16 + (lane & 15)) * 32 + (lane >> 4) * 8);
#pragma unroll
        for (int i = 0; i < 4; ++i)
#pragma unroll
            for (int j = 0; j < 4; ++j)
                acc[i][j] = __builtin_amdgcn_mfma_f32_16x16x32_bf16(a[i], b[j], acc[i][j], 0, 0, 0);
        __syncthreads();
    }

    // C/D layout: col = lane&15, row = (lane>>4)*4 + reg
#pragma unroll
    for (int i = 0; i < 4; ++i) {
#pragma unroll
        for (int j = 0; j < 4; ++j) {
            const int col = bn * 128 + wn * 64 + j * 16 + (lane & 15);
#pragma unroll
            for (int r2 = 0; r2 < 4; ++r2) {
                const int row = bm * 128 + wm * 64 + i * 16 + (lane >> 4) * 4 + r2;
                C[(size_t)row * N + col] = __float2bfloat16(acc[i][j][r2]);
            }
        }
    }
}

// --- fractional LIF scan: time-tiled, ILP-parallel memory term --------------
// One thread per neuron. History stored TRANSPOSED in LDS: hist[k][lane]
// (stride-1 across lanes -> 2-way bank aliasing = free; no cross-thread data,
// so no __syncthreads needed between tiles).
// Per tile of TB=16 steps:
//   old-phase: old[i] = sum_{k<n0} h[k]*c[n0+i-k], 16 independent FMA chains,
//              k ascending (matches original summation order).
//   seq-phase: mem ready in old[i]; new dV scatter-forwarded to old[i'>i]
//              (j-ascending order, matching the original single-chain order).
// FINAL=false: Iin bf16, write spikes bf16 (for GEMM2)
// FINAL=true : Iin f32,  write spikes f32 + mems f32 (d_out)
template <bool FINAL>
__global__ __launch_bounds__(64) void flif_scan_kernel(const void* __restrict__ Iin,
                                                       void* __restrict__ spikes,
                                                       float* __restrict__ mems,
                                                       const float* __restrict__ ctab,
                                                       int NT, float kappa) {
    __shared__ float hist[T_STEPS * 64];        // [k][lane], 32 KB
    __shared__ __attribute__((aligned(16))) float cs[192];
    const int lane = threadIdx.x;
    const int nid  = blockIdx.x * 64 + lane;

    // prefetch tile-0 inputs before anything else (latency hidden by c-load+sync)
    float pfI[TB];
#pragma unroll
    for (int i = 0; i < TB; ++i) {
        if (FINAL) pfI[i] = ((const float*)Iin)[(size_t)i * NT + nid];
        else       pfI[i] = __bfloat162float(((const __hip_bfloat16*)Iin)[(size_t)i * NT + nid]);
    }

    for (int j = lane; j < 192; j += 64) cs[j] = ctab[j];
    __syncthreads();

    // small c window for within-tile terms (c[1..15]; index 0 unused)
    float cn[TB];
#pragma unroll
    for (int j = 0; j < TB; ++j) cn[j] = cs[j];

    float V = -70.f;

    for (int t = 0; t < T_STEPS / TB; ++t) {
        const int n0 = t * TB;              // 0-based step index base of this tile

        // refill input prefetch for this tile (t=0 already loaded above)
        if (t > 0) {
#pragma unroll
            for (int i = 0; i < TB; ++i) {
                if (FINAL) pfI[i] = ((const float*)Iin)[(size_t)(n0 + i) * NT + nid];
                else       pfI[i] = __bfloat162float(((const __hip_bfloat16*)Iin)[(size_t)(n0 + i) * NT + nid]);
            }
        }

        float old_[TB];
#pragma unroll
        for (int i = 0; i < TB; ++i) old_[i] = 0.f;

        // ---- old-phase: chunks of 16 history slots, k ascending ----
        for (int k0 = 0; k0 < n0; k0 += 16) {
            const int base = n0 - k0 - 15;  // >=1, and base-1 is a multiple of 16
            float cw[32];                   // cw[j] = c[base-1+j], j=0..31
#pragma unroll
            for (int q = 0; q < 8; ++q) {
                const float4 cv = *reinterpret_cast<const float4*>(cs + (base - 1) + 4 * q);
                cw[4 * q + 0] = cv.x; cw[4 * q + 1] = cv.y;
                cw[4 * q + 2] = cv.z; cw[4 * q + 3] = cv.w;
            }
#pragma unroll
            for (int kk = 0; kk < 16; ++kk) {
                const float hv = hist[(k0 + kk) * 64 + lane];
                // c[n0+i-(k0+kk)] = c[base-1 + (16-kk+i)]
#pragma unroll
                for (int i = 0; i < TB; ++i)
                    old_[i] += hv * cw[16 - kk + i];
            }
        }

        // ---- sequential phase: 16 steps, short critical chain ----
#pragma unroll
        for (int i = 0; i < TB; ++i) {
            const int nm1 = n0 + i;                       // 0-based step index
            const float Iv = pfI[i];
            const float f  = (-0.025f * (V + 70.f) + Iv) * 2.0f;   // /CM, CM=0.5
            const float Vn = kappa * f + V - old_[i];
            const bool  sp = (Vn >= -50.f);
            const float Vr = sp ? -70.f : Vn;
            const float dv = Vr - V;
            hist[nm1 * 64 + lane] = dv;
            // scatter-forward this dV into the remaining steps of the tile
#pragma unroll
            for (int i2 = i + 1; i2 < TB; ++i2)
                old_[i2] += dv * cn[i2 - i];
            if (FINAL) {
                ((float*)spikes)[(size_t)nm1 * NT + nid] = sp ? 1.f : 0.f;
                mems[(size_t)nm1 * NT + nid] = Vr;
            } else {
                ((__hip_bfloat16*)spikes)[(size_t)nm1 * NT + nid] = __float2bfloat16(sp ? 1.f : 0.f);
            }
            V = Vr;
        }
    }
}

// --- GEMM2: Io[r][o] = sum_h S[r][h]*Wo[o][h], one wave per row (f32 out) ---
__global__ __launch_bounds__(256) void gemm2_kernel(const __hip_bfloat16* __restrict__ S,
                                                    const float* __restrict__ Wo,
                                                    float* __restrict__ Io) {
    const int wave = threadIdx.x >> 6, lane = threadIdx.x & 63;
    const int r = blockIdx.x * 4 + wave;
    u16x8 raw = *reinterpret_cast<const u16x8*>(S + (size_t)r * NH + lane * 8);
    float s[8];
#pragma unroll
    for (int j = 0; j < 8; ++j) s[j] = b2f_bits(raw[j]);
#pragma unroll
    for (int o = 0; o < NO; ++o) {
        const float* w = Wo + (size_t)o * NH + lane * 8;
        float a = 0.f;
#pragma unroll
        for (int j = 0; j < 8; ++j) a += s[j] * w[j];
#pragma unroll
        for (int off = 32; off; off >>= 1) a += __shfl_xor(a, off);
        if (lane == o) Io[(size_t)r * NO + o] = a;
    }
}

extern "C" void kernel_launch(void* const* d_in, const int* in_sizes, int n_in,
                              void* d_out, int out_size, void* d_ws, size_t ws_size,
                              hipStream_t stream) {
    const float* data = (const float*)d_in[0];   // [64][128][784]
    const float* Wh   = (const float*)d_in[1];   // [512][784]
    const float* Wo   = (const float*)d_in[2];   // [10][512]
    float* out = (float*)d_out;                  // f32! spikes then mems

    char* ws = (char*)d_ws;
    size_t off = 0;
    auto alloc = [&](size_t bytes) { void* p = ws + off; off += (bytes + 255) & ~255ull; return p; };
    __hip_bfloat16* Ab   = (__hip_bfloat16*)alloc((size_t)M1 * NIP * 2);  // 13.1 MB
    __hip_bfloat16* Whb  = (__hip_bfloat16*)alloc((size_t)NH * NIP * 2);  // 0.8 MB
    __hip_bfloat16* Ih   = (__hip_bfloat16*)alloc((size_t)M1 * NH * 2);   // 8.4 MB
    __hip_bfloat16* Sh   = (__hip_bfloat16*)alloc((size_t)M1 * NH * 2);   // 8.4 MB
    float*          Io   = (float*)alloc((size_t)M1 * NO * 4);            // 0.33 MB
    float*          ctab = (float*)alloc(192 * 4);

    const float kappa = (float)(std::pow(0.1, 0.2) * std::tgamma(1.8));

    init_c_kernel<<<1, 256, 0, stream>>>(ctab);
    cast_pad_kernel<<<(M1 * 200 + 255) / 256, 256, 0, stream>>>(data, Ab, M1, 1);
    cast_pad_kernel<<<(NH * 200 + 255) / 256, 256, 0, stream>>>(Wh, Whb, NH, 0);

    dim3 g1(64, 4, 1);   // M/128 x N/128
    gemm_bf16_kernel<<<g1, 256, 0, stream>>>(Ab, Whb, Ih, NH, NIP);

    flif_scan_kernel<false><<<NT_H / 64, 64, 0, stream>>>(Ih, Sh, nullptr, ctab, NT_H, kappa);

    gemm2_kernel<<<M1 / 4, 256, 0, stream>>>(Sh, Wo, Io);

    flif_scan_kernel<true><<<NT_O / 64, 64, 0, stream>>>(Io, out, out + OUT_HALF, ctab, NT_O, kappa);
}